// Round 7
// baseline (450.895 us; speedup 1.0000x reference)
//
#include <hip/hip_runtime.h>
#include <hip/hip_bf16.h>
#include <hip/hip_fp16.h>

// TinyTransformerBlock: B=4, S=2048, D=1024, DFF=4096, fp32 in/out.
// R7: add gemm_big — 256x256 block tile, 4 waves each owning a 128x128 tile
// (acc[8][8]=256 regs, 1 wave/SIMD). Fragment LDS traffic per MAC drops
// 0.0625 -> 0.031 B (perimeter/area), making MFMA the binding pipe
// (32 ds_read vs 128 MFMA per wave per BK=64 iter). Used for qk / scores /
// FFN1 (N>=2048 keeps grid >= 256 blocks). N=1024 GEMMs keep the R6 K-split
// kernel. XOR-swizzled staging everywhere: zero bank conflicts.

typedef _Float16 f16;
typedef __attribute__((ext_vector_type(8))) _Float16 f16x8;
typedef __attribute__((ext_vector_type(4))) _Float16 f16x4;
typedef __attribute__((ext_vector_type(4))) float f32x4;

#define BM 128
#define BN 128
#define BK 64

__device__ inline void gload16(const void* g, void* l) {
    __builtin_amdgcn_global_load_lds(
        (const __attribute__((address_space(1))) void*)g,
        (__attribute__((address_space(3))) void*)l, 16, 0, 0);
}

// ---------------- big-tile kernel: 256x256, wave = 128x128 ----------------
// EPI: 0 = f16 store, 1 = f16 relu store, 2 = f32 store
template<int EPI>
__global__ __launch_bounds__(256, 1)
void gemm_big(const f16* __restrict__ A, const f16* __restrict__ Bt,
              void* __restrict__ Cv,
              int K, int lda, int ldb, int ldc,
              long long sA, long long sB, long long sC)
{
    __shared__ f16 Ash[256 * BK];   // 32 KB
    __shared__ f16 Bsh[256 * BK];   // 32 KB

    const int t = threadIdx.x;
    const int z = blockIdx.z;
    A  += (size_t)z * sA;
    Bt += (size_t)z * sB;

    const int bm0 = blockIdx.x * 256;   // M-tile fastest (XCD pinning)
    const int bn0 = blockIdx.y * 256;

    const int lane = t & 63;
    const int wid  = t >> 6;
    const int quad = lane >> 4;
    const int m16  = lane & 15;
    const int wm   = (wid & 1) * 128;
    const int wnn  = (wid >> 1) * 128;

    // staging: issue i covers rows i*32..i*32+31; chunk c=t -> row t>>3,
    // slot t&7, source k-half XOR-swizzled.
    const int r0 = t >> 3;
    const int kc = ((t & 7) ^ (r0 & 7)) * 8;
    const char* gA0 = (const char*)(A  + (size_t)(bm0 + r0) * lda + kc);
    const char* gB0 = (const char*)(Bt + (size_t)(bn0 + r0) * ldb + kc);
    const long long aStep = 64LL * lda;   // 32 rows in bytes
    const long long bStep = 64LL * ldb;
    char* lA = (char*)Ash + (wid << 10);
    char* lB = (char*)Bsh + (wid << 10);

    f32x4 acc[8][8] = {};   // 128x128 per wave

    const int nk = K / BK;
    #define ISSUE(kt) do { const long long ko = (long long)(kt) * 128;  \
        _Pragma("unroll")                                               \
        for (int ii = 0; ii < 8; ++ii) {                                \
            gload16(gA0 + ii * aStep + ko, lA + ii * 4096);             \
            gload16(gB0 + ii * bStep + ko, lB + ii * 4096);             \
        } } while (0)

    const int swz = m16 & 7;

    ISSUE(0);
    for (int kt = 0; kt < nk; ++kt) {
        __syncthreads();                       // tile kt resident
        f16x8 af[2][8], bf[2][8];
        #pragma unroll
        for (int s = 0; s < 2; ++s) {
            const int ha = (((s << 2) | quad) ^ swz) * 8;
            #pragma unroll
            for (int i = 0; i < 8; ++i) {
                af[s][i] = *(const f16x8*)&Ash[(wm + i * 16 + m16) * BK + ha];
                bf[s][i] = *(const f16x8*)&Bsh[(wnn + i * 16 + m16) * BK + ha];
            }
        }
        __syncthreads();                       // all frag reads done
        if (kt + 1 < nk) ISSUE(kt + 1);        // prefetch overlaps MFMA
        #pragma unroll
        for (int s = 0; s < 2; ++s)
            #pragma unroll
            for (int i = 0; i < 8; ++i)
                #pragma unroll
                for (int j = 0; j < 8; ++j)
                    acc[i][j] = __builtin_amdgcn_mfma_f32_16x16x32_f16(
                                    af[s][i], bf[s][j], acc[i][j], 0, 0, 0);
    }
    #undef ISSUE

    // C/D: col = lane&15, row = quad*4 + reg
    if (EPI <= 1) {
        f16* C = (f16*)Cv + (size_t)z * sC;
        #pragma unroll
        for (int i = 0; i < 8; ++i)
            #pragma unroll
            for (int ri = 0; ri < 4; ++ri) {
                const size_t row = (size_t)(bm0 + wm + i * 16 + quad * 4 + ri);
                f16* cp = C + row * ldc + (bn0 + wnn + m16);
                #pragma unroll
                for (int j = 0; j < 8; ++j) {
                    float v = acc[i][j][ri];
                    if (EPI == 1) v = fmaxf(v, 0.0f);
                    cp[j * 16] = (f16)v;
                }
            }
    } else {
        float* C = (float*)Cv + (size_t)z * sC;
        #pragma unroll
        for (int i = 0; i < 8; ++i)
            #pragma unroll
            for (int ri = 0; ri < 4; ++ri) {
                const size_t row = (size_t)(bm0 + wm + i * 16 + quad * 4 + ri);
                float* cp = C + row * ldc + (bn0 + wnn + m16);
                #pragma unroll
                for (int j = 0; j < 8; ++j)
                    cp[j * 16] = acc[i][j][ri];
            }
    }
}

// ---------------- R6 K-split kernel (128x128), for N=1024 GEMMs ----------
// EPI: 0 = f16 store, 1 = f16 relu store, 2 = f32 store, 3 = f32 + residual
template<int EPI>
__global__ __launch_bounds__(256, 2)
void gemm_f16(const f16* __restrict__ A, const f16* __restrict__ Bt,
              const float* __restrict__ Res, void* __restrict__ Cv,
              int K, int lda, int ldb, int ldc,
              long long sA, long long sB, long long sC)
{
    __shared__ char smem[32 * 1024];
    f16* Ash = (f16*)smem;
    f16* Bsh = (f16*)(smem + 16384);
    float* xbuf = (float*)smem;

    const int t = threadIdx.x;
    const int z = blockIdx.z;
    A  += (size_t)z * sA;
    Bt += (size_t)z * sB;

    const int bm0 = blockIdx.x * BM;
    const int bn0 = blockIdx.y * BN;

    const int lane = t & 63;
    const int wid  = t >> 6;
    const int quad = lane >> 4;
    const int m16  = lane & 15;
    const int ks   = wid & 1;
    const int wn64 = (wid >> 1) * 64;

    const int r0 = t >> 3;
    const int kc = ((t & 7) ^ (r0 & 7)) * 8;
    const char* gA[4]; const char* gB[4];
    #pragma unroll
    for (int i = 0; i < 4; ++i) {
        gA[i] = (const char*)(A  + (size_t)(bm0 + i * 32 + r0) * lda + kc);
        gB[i] = (const char*)(Bt + (size_t)(bn0 + i * 32 + r0) * ldb + kc);
    }
    char* lA = (char*)Ash + (wid << 10);
    char* lB = (char*)Bsh + (wid << 10);

    f32x4 acc[8][4] = {};

    const int nk = K / BK;
    #define ISSUE(kt) do { const int ko = (kt) * 128;   \
        gload16(gA[0] + ko, lA);                        \
        gload16(gA[1] + ko, lA + 4096);                 \
        gload16(gA[2] + ko, lA + 8192);                 \
        gload16(gA[3] + ko, lA + 12288);                \
        gload16(gB[0] + ko, lB);                        \
        gload16(gB[1] + ko, lB + 4096);                 \
        gload16(gB[2] + ko, lB + 8192);                 \
        gload16(gB[3] + ko, lB + 12288); } while (0)

    const int swz = m16 & 7;
    const int ha  = ((ks * 4 + quad) ^ swz) * 8;

    ISSUE(0);
    for (int kt = 0; kt < nk; ++kt) {
        __syncthreads();
        f16x8 af[8], bf[4];
        #pragma unroll
        for (int i = 0; i < 8; ++i)
            af[i] = *(const f16x8*)&Ash[(i * 16 + m16) * BK + ha];
        #pragma unroll
        for (int j = 0; j < 4; ++j)
            bf[j] = *(const f16x8*)&Bsh[(wn64 + j * 16 + m16) * BK + ha];
        __syncthreads();
        if (kt + 1 < nk) ISSUE(kt + 1);
        #pragma unroll
        for (int i = 0; i < 8; ++i)
            #pragma unroll
            for (int j = 0; j < 4; ++j)
                acc[i][j] = __builtin_amdgcn_mfma_f32_16x16x32_f16(
                                af[i], bf[j], acc[i][j], 0, 0, 0);
    }
    #undef ISSUE

    float* xb = xbuf + (wid >> 1) * 4096;
    #define XIDX(row, col) ((row) * 64 + ((col) ^ (((row) & 4) << 2)))
    if (ks == 1) {
        #pragma unroll
        for (int i = 0; i < 4; ++i)
            #pragma unroll
            for (int j = 0; j < 4; ++j)
                #pragma unroll
                for (int ri = 0; ri < 4; ++ri)
                    xb[XIDX(i * 16 + quad * 4 + ri, j * 16 + m16)] = acc[i][j][ri];
    }
    __syncthreads();
    if (ks == 0) {
        #pragma unroll
        for (int i = 0; i < 4; ++i)
            #pragma unroll
            for (int j = 0; j < 4; ++j)
                #pragma unroll
                for (int ri = 0; ri < 4; ++ri)
                    acc[i][j][ri] += xb[XIDX(i * 16 + quad * 4 + ri, j * 16 + m16)];
    }
    __syncthreads();
    if (ks == 0) {
        #pragma unroll
        for (int i = 0; i < 4; ++i)
            #pragma unroll
            for (int j = 0; j < 4; ++j)
                #pragma unroll
                for (int ri = 0; ri < 4; ++ri)
                    xb[XIDX(i * 16 + quad * 4 + ri, j * 16 + m16)] = acc[i + 4][j][ri];
    }
    __syncthreads();
    if (ks == 1) {
        #pragma unroll
        for (int i = 0; i < 4; ++i)
            #pragma unroll
            for (int j = 0; j < 4; ++j)
                #pragma unroll
                for (int ri = 0; ri < 4; ++ri)
                    acc[i + 4][j][ri] += xb[XIDX(i * 16 + quad * 4 + ri, j * 16 + m16)];
    }
    #undef XIDX

    #define STORE_TILE(IB, RB)                                                  \
        do {                                                                    \
            if (EPI <= 1) {                                                     \
                f16* C = (f16*)Cv + (size_t)z * sC;                             \
                _Pragma("unroll")                                               \
                for (int i = 0; i < 4; ++i)                                     \
                    _Pragma("unroll")                                           \
                    for (int ri = 0; ri < 4; ++ri) {                            \
                        const size_t row = (size_t)(bm0 + (RB) + i * 16 + quad * 4 + ri); \
                        f16* cp = C + row * ldc + (bn0 + wn64 + m16);           \
                        _Pragma("unroll")                                       \
                        for (int j = 0; j < 4; ++j) {                           \
                            float v = acc[(IB) + i][j][ri];                     \
                            if (EPI == 1) v = fmaxf(v, 0.0f);                   \
                            cp[j * 16] = (f16)v;                                \
                        }                                                       \
                    }                                                           \
            } else {                                                            \
                float* C = (float*)Cv + (size_t)z * sC;                         \
                _Pragma("unroll")                                               \
                for (int i = 0; i < 4; ++i)                                     \
                    _Pragma("unroll")                                           \
                    for (int ri = 0; ri < 4; ++ri) {                            \
                        const size_t row = (size_t)(bm0 + (RB) + i * 16 + quad * 4 + ri); \
                        float* cp = C + row * ldc + (bn0 + wn64 + m16);         \
                        const float* rp = (EPI == 3)                            \
                            ? Res + row * ldc + (bn0 + wn64 + m16) : nullptr;   \
                        _Pragma("unroll")                                       \
                        for (int j = 0; j < 4; ++j) {                           \
                            float v = acc[(IB) + i][j][ri];                     \
                            if (EPI == 3) v += rp[j * 16];                      \
                            cp[j * 16] = v;                                     \
                        }                                                       \
                    }                                                           \
            }                                                                   \
        } while (0)

    if (ks == 0) STORE_TILE(0, 0);
    else         STORE_TILE(4, 64);
    #undef STORE_TILE
}

// fp32 [R][C] -> fp16 [C][R], 4 sources (z selects), all R=C=1024
__global__ __launch_bounds__(256)
void transpose_cast4(const float* __restrict__ s0, const float* __restrict__ s1,
                     const float* __restrict__ s2, const float* __restrict__ s3,
                     f16* __restrict__ d0, f16* __restrict__ d1,
                     f16* __restrict__ d2, f16* __restrict__ d3)
{
    const int R = 1024, C = 1024;
    const int z = blockIdx.z;
    const float* in = (z == 0) ? s0 : (z == 1) ? s1 : (z == 2) ? s2 : s3;
    f16* out = (z == 0) ? d0 : (z == 1) ? d1 : (z == 2) ? d2 : d3;
    __shared__ float tile[64][65];
    const int c0 = blockIdx.x * 64, r0 = blockIdx.y * 64;
    const int tc = threadIdx.x & 63, tr = threadIdx.x >> 6;
    #pragma unroll
    for (int i = 0; i < 16; ++i)
        tile[tr + i * 4][tc] = in[(size_t)(r0 + tr + i * 4) * C + c0 + tc];
    __syncthreads();
    #pragma unroll
    for (int i = 0; i < 16; ++i)
        out[(size_t)(c0 + tr + i * 4) * R + r0 + tc] = (f16)tile[tc][tr + i * 4];
}

// fp32 [R][C] -> fp16 [C][R]
__global__ __launch_bounds__(256)
void transpose_cast(const float* __restrict__ in, f16* __restrict__ out,
                    int R, int C)
{
    __shared__ float tile[64][65];
    const int c0 = blockIdx.x * 64, r0 = blockIdx.y * 64;
    const int tc = threadIdx.x & 63, tr = threadIdx.x >> 6;
    #pragma unroll
    for (int i = 0; i < 16; ++i)
        tile[tr + i * 4][tc] = in[(size_t)(r0 + tr + i * 4) * C + c0 + tc];
    __syncthreads();
    #pragma unroll
    for (int i = 0; i < 16; ++i)
        out[(size_t)(c0 + tr + i * 4) * R + r0 + tc] = (f16)tile[tc][tr + i * 4];
}

__global__ __launch_bounds__(256)
void cast_f16(const float* __restrict__ in, f16* __restrict__ out)
{
    const size_t i = ((size_t)blockIdx.x * 256 + threadIdx.x) * 4;
    float4 v = *(const float4*)(in + i);
    f16x4 o; o.x = (f16)v.x; o.y = (f16)v.y; o.z = (f16)v.z; o.w = (f16)v.w;
    *(f16x4*)(out + i) = o;
}

// row softmax over 2048 fp32 -> fp16
__global__ __launch_bounds__(256)
void softmax_f16(const float* __restrict__ S, f16* __restrict__ P)
{
    __shared__ float red[256];
    const float* p = S + (size_t)blockIdx.x * 2048;
    f16* q = P + (size_t)blockIdx.x * 2048;
    const int t = threadIdx.x;

    float4 u0 = *(const float4*)(p + t * 4);
    float4 u1 = *(const float4*)(p + 1024 + t * 4);

    float m = fmaxf(fmaxf(fmaxf(u0.x, u0.y), fmaxf(u0.z, u0.w)),
                    fmaxf(fmaxf(u1.x, u1.y), fmaxf(u1.z, u1.w)));
    red[t] = m;
    __syncthreads();
    #pragma unroll
    for (int s = 128; s > 0; s >>= 1) {
        if (t < s) red[t] = fmaxf(red[t], red[t + s]);
        __syncthreads();
    }
    const float rowmax = red[0];
    __syncthreads();

    u0.x = __expf(u0.x - rowmax); u0.y = __expf(u0.y - rowmax);
    u0.z = __expf(u0.z - rowmax); u0.w = __expf(u0.w - rowmax);
    u1.x = __expf(u1.x - rowmax); u1.y = __expf(u1.y - rowmax);
    u1.z = __expf(u1.z - rowmax); u1.w = __expf(u1.w - rowmax);

    red[t] = (u0.x + u0.y + u0.z + u0.w) + (u1.x + u1.y + u1.z + u1.w);
    __syncthreads();
    #pragma unroll
    for (int s = 128; s > 0; s >>= 1) {
        if (t < s) red[t] += red[t + s];
        __syncthreads();
    }
    const float inv = 1.0f / red[0];

    f16x4 o0, o1;
    o0.x = (f16)(u0.x * inv); o0.y = (f16)(u0.y * inv);
    o0.z = (f16)(u0.z * inv); o0.w = (f16)(u0.w * inv);
    o1.x = (f16)(u1.x * inv); o1.y = (f16)(u1.y * inv);
    o1.z = (f16)(u1.z * inv); o1.w = (f16)(u1.w * inv);
    *(f16x4*)(q + t * 4)        = o0;
    *(f16x4*)(q + 1024 + t * 4) = o1;
}

extern "C" void kernel_launch(void* const* d_in, const int* in_sizes, int n_in,
                              void* d_out, int out_size, void* d_ws, size_t ws_size,
                              hipStream_t stream)
{
    const float* x  = (const float*)d_in[0];
    const float* wq = (const float*)d_in[1];
    const float* wk = (const float*)d_in[2];
    const float* wv = (const float*)d_in[3];
    const float* wo = (const float*)d_in[4];
    const float* w1 = (const float*)d_in[5];
    const float* w2 = (const float*)d_in[6];
    float* out = (float*)d_out;

    const int S = 2048, D = 1024, DFF = 4096, Bb = 4;
    const int NTOK = Bb * S;  // 8192

    // workspace (halves unless noted); total 152 MB
    f16* W    = (f16*)d_ws;
    f16* xh   = W;                           // 8M
    f16* wqkT = xh   + (size_t)NTOK * D;     // 2M  ([2048][1024]: wqT | wkT)
    f16* wvT  = wqkT + (size_t)2 * D * D;    // 1M
    f16* woT  = wvT  + (size_t)D * D;        // 1M
    f16* w1T  = woT  + (size_t)D * D;        // 4M
    f16* w2T  = w1T  + (size_t)D * DFF;      // 4M
    f16* qk   = w2T  + (size_t)DFF * D;      // 16M ([8192][2048])
    f16* vT   = qk   + (size_t)NTOK * 2 * D; // 8M  ([1024][8192])
    float* sb = (float*)(vT + (size_t)D * NTOK);  // 16M fp32 (64 MB)
    f16* ph   = qk;                          // probs overwrite q|k (16M)
    f16* at   = xh;                          // attn overwrites xh
    f16* pj   = vT;                          // proj overwrites vT
    f16* hd   = (f16*)sb;                    // hidden overwrites scores

    dim3 blk(256);

    // casts / transposes
    cast_f16<<<dim3(NTOK * D / 1024), blk, 0, stream>>>(x, xh);
    transpose_cast4<<<dim3(D / 64, D / 64, 4), blk, 0, stream>>>(
        wq, wk, wv, wo, wqkT, wqkT + (size_t)D * D, wvT, woT);
    transpose_cast<<<dim3(DFF / 64, D / 64), blk, 0, stream>>>(w1, w1T, D, DFF);
    transpose_cast<<<dim3(D / 64, DFF / 64), blk, 0, stream>>>(w2, w2T, DFF, D);

    // qk = xh @ wqkT'   [8192][2048]   big-tile
    gemm_big<0><<<dim3(NTOK / 256, 2 * D / 256, 1), blk, 0, stream>>>(
        xh, wqkT, qk, D, D, D, 2 * D, 0, 0, 0);
    // vT = wvT @ xh'    [1024][8192]
    gemm_f16<0><<<dim3(D / BM, NTOK / BN, 1), blk, 0, stream>>>(
        wvT, xh, nullptr, vT, D, D, D, NTOK, 0, 0, 0);

    // scores[b] = q_b @ k_b'  fp32 [2048][2048] x4   big-tile
    gemm_big<2><<<dim3(S / 256, S / 256, Bb), blk, 0, stream>>>(
        qk, qk + D, sb, D, 2 * D, 2 * D, S,
        (long long)S * 2 * D, (long long)S * 2 * D, (long long)S * S);

    // softmax -> fp16 probs (overwrites qk)
    softmax_f16<<<dim3(NTOK), blk, 0, stream>>>(sb, ph);

    // attn[b] = p_b @ (vT[:, b-slice])'   [2048][1024] x4
    gemm_f16<0><<<dim3(S / BM, D / BN, Bb), blk, 0, stream>>>(
        ph, vT, nullptr, at, S, S, NTOK, D,
        (long long)S * S, (long long)S, (long long)S * D);

    // proj = at @ woT'
    gemm_f16<0><<<dim3(NTOK / BM, D / BN, 1), blk, 0, stream>>>(
        at, woT, nullptr, pj, D, D, D, D, 0, 0, 0);

    // hidden = relu(pj @ w1T')   [8192][4096]   big-tile
    gemm_big<1><<<dim3(NTOK / 256, DFF / 256, 1), blk, 0, stream>>>(
        pj, w1T, hd, D, D, D, DFF, 0, 0, 0);

    // out = hd @ w2T' + x   fp32 [8192][1024]
    gemm_f16<3><<<dim3(NTOK / BM, D / BN, 1), blk, 0, stream>>>(
        hd, w2T, x, out, DFF, DFF, DFF, D, 0, 0, 0);
}

// Round 8
// 427.555 us; speedup vs baseline: 1.0546x; 1.0546x over previous
//
#include <hip/hip_runtime.h>
#include <hip/hip_bf16.h>
#include <hip/hip_fp16.h>

// TinyTransformerBlock: B=4, S=2048, D=1024, DFF=4096, fp32 in/out.
// R8: algebraic FLOP removal. scores = x(wq wk^T)x^T, P-side: (P(x wv))wo =
// P(x (wv wo)). Precompute Wqk^T = wk@wq^T and Wvo^T via a dedicated small
// D x D kernel (64x64 tiles, 4-way wave K-split, grid 512). Eliminates the
// k-projection and the whole proj GEMM (275 -> 245 GF) plus one 16 MB
// intermediate. FFN1 uses the R4-style no-split kernel (measured 941 TF).
// Softmax is in-place (f16 probs into the fp32 scores rows, lda=4096).

typedef _Float16 f16;
typedef __attribute__((ext_vector_type(8))) _Float16 f16x8;
typedef __attribute__((ext_vector_type(4))) _Float16 f16x4;
typedef __attribute__((ext_vector_type(4))) float f32x4;

#define BM 128
#define BN 128
#define BK 64

__device__ inline void gload16(const void* g, void* l) {
    __builtin_amdgcn_global_load_lds(
        (const __attribute__((address_space(1))) void*)g,
        (__attribute__((address_space(3))) void*)l, 16, 0, 0);
}

// ---------------- R6 K-split kernel (128x128) — long-K / general ----------
// EPI: 0 = f16 store, 1 = f16 relu store, 2 = f32 store, 3 = f32 + residual
template<int EPI>
__global__ __launch_bounds__(256, 2)
void gemm_f16(const f16* __restrict__ A, const f16* __restrict__ Bt,
              const float* __restrict__ Res, void* __restrict__ Cv,
              int K, int lda, int ldb, int ldc,
              long long sA, long long sB, long long sC)
{
    __shared__ char smem[32 * 1024];
    f16* Ash = (f16*)smem;
    f16* Bsh = (f16*)(smem + 16384);
    float* xbuf = (float*)smem;

    const int t = threadIdx.x;
    const int z = blockIdx.z;
    A  += (size_t)z * sA;
    Bt += (size_t)z * sB;

    const int bm0 = blockIdx.x * BM;
    const int bn0 = blockIdx.y * BN;

    const int lane = t & 63;
    const int wid  = t >> 6;
    const int quad = lane >> 4;
    const int m16  = lane & 15;
    const int ks   = wid & 1;
    const int wn64 = (wid >> 1) * 64;

    const int r0 = t >> 3;
    const int kc = ((t & 7) ^ (r0 & 7)) * 8;
    const char* gA[4]; const char* gB[4];
    #pragma unroll
    for (int i = 0; i < 4; ++i) {
        gA[i] = (const char*)(A  + (size_t)(bm0 + i * 32 + r0) * lda + kc);
        gB[i] = (const char*)(Bt + (size_t)(bn0 + i * 32 + r0) * ldb + kc);
    }
    char* lA = (char*)Ash + (wid << 10);
    char* lB = (char*)Bsh + (wid << 10);

    f32x4 acc[8][4] = {};

    const int nk = K / BK;
    #define ISSUE(kt) do { const int ko = (kt) * 128;   \
        gload16(gA[0] + ko, lA);                        \
        gload16(gA[1] + ko, lA + 4096);                 \
        gload16(gA[2] + ko, lA + 8192);                 \
        gload16(gA[3] + ko, lA + 12288);                \
        gload16(gB[0] + ko, lB);                        \
        gload16(gB[1] + ko, lB + 4096);                 \
        gload16(gB[2] + ko, lB + 8192);                 \
        gload16(gB[3] + ko, lB + 12288); } while (0)

    const int swz = m16 & 7;
    const int ha  = ((ks * 4 + quad) ^ swz) * 8;

    ISSUE(0);
    for (int kt = 0; kt < nk; ++kt) {
        __syncthreads();
        f16x8 af[8], bf[4];
        #pragma unroll
        for (int i = 0; i < 8; ++i)
            af[i] = *(const f16x8*)&Ash[(i * 16 + m16) * BK + ha];
        #pragma unroll
        for (int j = 0; j < 4; ++j)
            bf[j] = *(const f16x8*)&Bsh[(wn64 + j * 16 + m16) * BK + ha];
        __syncthreads();
        if (kt + 1 < nk) ISSUE(kt + 1);
        #pragma unroll
        for (int i = 0; i < 8; ++i)
            #pragma unroll
            for (int j = 0; j < 4; ++j)
                acc[i][j] = __builtin_amdgcn_mfma_f32_16x16x32_f16(
                                af[i], bf[j], acc[i][j], 0, 0, 0);
    }
    #undef ISSUE

    float* xb = xbuf + (wid >> 1) * 4096;
    #define XIDX(row, col) ((row) * 64 + ((col) ^ (((row) & 4) << 2)))
    if (ks == 1) {
        #pragma unroll
        for (int i = 0; i < 4; ++i)
            #pragma unroll
            for (int j = 0; j < 4; ++j)
                #pragma unroll
                for (int ri = 0; ri < 4; ++ri)
                    xb[XIDX(i * 16 + quad * 4 + ri, j * 16 + m16)] = acc[i][j][ri];
    }
    __syncthreads();
    if (ks == 0) {
        #pragma unroll
        for (int i = 0; i < 4; ++i)
            #pragma unroll
            for (int j = 0; j < 4; ++j)
                #pragma unroll
                for (int ri = 0; ri < 4; ++ri)
                    acc[i][j][ri] += xb[XIDX(i * 16 + quad * 4 + ri, j * 16 + m16)];
    }
    __syncthreads();
    if (ks == 0) {
        #pragma unroll
        for (int i = 0; i < 4; ++i)
            #pragma unroll
            for (int j = 0; j < 4; ++j)
                #pragma unroll
                for (int ri = 0; ri < 4; ++ri)
                    xb[XIDX(i * 16 + quad * 4 + ri, j * 16 + m16)] = acc[i + 4][j][ri];
    }
    __syncthreads();
    if (ks == 1) {
        #pragma unroll
        for (int i = 0; i < 4; ++i)
            #pragma unroll
            for (int j = 0; j < 4; ++j)
                #pragma unroll
                for (int ri = 0; ri < 4; ++ri)
                    acc[i + 4][j][ri] += xb[XIDX(i * 16 + quad * 4 + ri, j * 16 + m16)];
    }
    #undef XIDX

    #define STORE_TILE(IB, RB)                                                  \
        do {                                                                    \
            if (EPI <= 1) {                                                     \
                f16* C = (f16*)Cv + (size_t)z * sC;                             \
                _Pragma("unroll")                                               \
                for (int i = 0; i < 4; ++i)                                     \
                    _Pragma("unroll")                                           \
                    for (int ri = 0; ri < 4; ++ri) {                            \
                        const size_t row = (size_t)(bm0 + (RB) + i * 16 + quad * 4 + ri); \
                        f16* cp = C + row * ldc + (bn0 + wn64 + m16);           \
                        _Pragma("unroll")                                       \
                        for (int j = 0; j < 4; ++j) {                           \
                            float v = acc[(IB) + i][j][ri];                     \
                            if (EPI == 1) v = fmaxf(v, 0.0f);                   \
                            cp[j * 16] = (f16)v;                                \
                        }                                                       \
                    }                                                           \
            } else {                                                            \
                float* C = (float*)Cv + (size_t)z * sC;                         \
                _Pragma("unroll")                                               \
                for (int i = 0; i < 4; ++i)                                     \
                    _Pragma("unroll")                                           \
                    for (int ri = 0; ri < 4; ++ri) {                            \
                        const size_t row = (size_t)(bm0 + (RB) + i * 16 + quad * 4 + ri); \
                        float* cp = C + row * ldc + (bn0 + wn64 + m16);         \
                        const float* rp = (EPI == 3)                            \
                            ? Res + row * ldc + (bn0 + wn64 + m16) : nullptr;   \
                        _Pragma("unroll")                                       \
                        for (int j = 0; j < 4; ++j) {                           \
                            float v = acc[(IB) + i][j][ri];                     \
                            if (EPI == 3) v += rp[j * 16];                      \
                            cp[j * 16] = v;                                     \
                        }                                                       \
                    }                                                           \
            }                                                                   \
        } while (0)

    if (ks == 0) STORE_TILE(0, 0);
    else         STORE_TILE(4, 64);
    #undef STORE_TILE
}

// ---------------- R4-style no-split kernel (128x128, wave=64x64) ----------
// Best measured for FFN1 (941 TF). EPI: 0 = f16, 1 = f16 relu.
template<int EPI>
__global__ __launch_bounds__(256, 2)
void gemm_ns(const f16* __restrict__ A, const f16* __restrict__ Bt,
             void* __restrict__ Cv,
             int K, int lda, int ldb, int ldc)
{
    __shared__ f16 Ash[BM * BK];
    __shared__ f16 Bsh[BN * BK];

    const int t = threadIdx.x;
    const int bm0 = blockIdx.x * BM;
    const int bn0 = blockIdx.y * BN;

    const int lane = t & 63;
    const int wid  = t >> 6;
    const int quad = lane >> 4;
    const int m16  = lane & 15;
    const int wm = (wid & 1) * 64;
    const int wn = (wid >> 1) * 64;

    const int r0 = t >> 3;
    const int kc = ((t & 7) ^ (r0 & 7)) * 8;
    const char* gA[4]; const char* gB[4];
    #pragma unroll
    for (int i = 0; i < 4; ++i) {
        gA[i] = (const char*)(A  + (size_t)(bm0 + i * 32 + r0) * lda + kc);
        gB[i] = (const char*)(Bt + (size_t)(bn0 + i * 32 + r0) * ldb + kc);
    }
    char* lA = (char*)Ash + (wid << 10);
    char* lB = (char*)Bsh + (wid << 10);

    f32x4 acc[4][4] = {};

    const int nk = K / BK;
    #define ISSUE(kt) do { const int ko = (kt) * 128;   \
        gload16(gA[0] + ko, lA);                        \
        gload16(gA[1] + ko, lA + 4096);                 \
        gload16(gA[2] + ko, lA + 8192);                 \
        gload16(gA[3] + ko, lA + 12288);                \
        gload16(gB[0] + ko, lB);                        \
        gload16(gB[1] + ko, lB + 4096);                 \
        gload16(gB[2] + ko, lB + 8192);                 \
        gload16(gB[3] + ko, lB + 12288); } while (0)

    const int swz = m16 & 7;

    ISSUE(0);
    for (int kt = 0; kt < nk; ++kt) {
        __syncthreads();
        f16x8 af[2][4], bf[2][4];
        #pragma unroll
        for (int s = 0; s < 2; ++s) {
            const int ha = (((s << 2) | quad) ^ swz) * 8;
            #pragma unroll
            for (int i = 0; i < 4; ++i) {
                af[s][i] = *(const f16x8*)&Ash[(wm + i * 16 + m16) * BK + ha];
                bf[s][i] = *(const f16x8*)&Bsh[(wn + i * 16 + m16) * BK + ha];
            }
        }
        __syncthreads();
        if (kt + 1 < nk) ISSUE(kt + 1);
        #pragma unroll
        for (int s = 0; s < 2; ++s)
            #pragma unroll
            for (int i = 0; i < 4; ++i)
                #pragma unroll
                for (int j = 0; j < 4; ++j)
                    acc[i][j] = __builtin_amdgcn_mfma_f32_16x16x32_f16(
                                    af[s][i], bf[s][j], acc[i][j], 0, 0, 0);
    }
    #undef ISSUE

    f16* C = (f16*)Cv;
    #pragma unroll
    for (int i = 0; i < 4; ++i)
        #pragma unroll
        for (int ri = 0; ri < 4; ++ri) {
            const size_t row = (size_t)(bm0 + wm + i * 16 + quad * 4 + ri);
            f16* cp = C + row * ldc + (bn0 + wn + m16);
            #pragma unroll
            for (int j = 0; j < 4; ++j) {
                float v = acc[i][j][ri];
                if (EPI == 1) v = fmaxf(v, 0.0f);
                cp[j * 16] = (f16)v;
            }
        }
}

// ---------------- small D x D kernel: two 1024^3 products in one launch ---
// z=0: C0 = A0 @ B0^T (wqkT = wk@wq^T); z=1: C1 = A1 @ B1^T (wvoT).
// 64x64 block tile, BK=128 staged, 4 waves each own a 32-wide k-quarter,
// cross-wave LDS tree-reduce; grid (16,16,2) = 512 blocks.
__global__ __launch_bounds__(256, 2)
void gemm_dd(const f16* __restrict__ A0, const f16* __restrict__ B0, f16* __restrict__ C0,
             const f16* __restrict__ A1, const f16* __restrict__ B1, f16* __restrict__ C1)
{
    const int LD = 1024;
    __shared__ char smem[32 * 1024];
    f16* Ash = (f16*)smem;             // 16 KB: 64 rows x 128 k
    f16* Bsh = (f16*)(smem + 16384);   // 16 KB
    float* xred = (float*)smem;        // reduce regions alias staging

    const int t = threadIdx.x;
    const int z = blockIdx.z;
    const f16* A = z ? A1 : A0;
    const f16* B = z ? B1 : B0;
    f16* C = z ? C1 : C0;

    const int bm0 = blockIdx.x * 64;
    const int bn0 = blockIdx.y * 64;

    const int lane = t & 63;
    const int wid  = t >> 6;            // wave = k-quarter ks
    const int quad = lane >> 4;
    const int m16  = lane & 15;

    // staging: chunk c = i*256 + t -> row c>>4 (256 B rows), slot c&15;
    // source k-chunk XOR-swizzled by row&15.
    const int rr = t >> 4;              // 0..15
    const int kc = ((t & 15) ^ (rr & 15)) * 8;
    const char* gA[4]; const char* gB[4];
    #pragma unroll
    for (int i = 0; i < 4; ++i) {
        gA[i] = (const char*)(A + (size_t)(bm0 + i * 16 + rr) * LD + kc);
        gB[i] = (const char*)(B + (size_t)(bn0 + i * 16 + rr) * LD + kc);
    }
    char* lA = (char*)Ash + (wid << 10);
    char* lB = (char*)Bsh + (wid << 10);

    f32x4 acc[4][4] = {};

    #define ISSUE(kt) do { const int ko = (kt) * 256;   \
        gload16(gA[0] + ko, lA);                        \
        gload16(gA[1] + ko, lA + 4096);                 \
        gload16(gA[2] + ko, lA + 8192);                 \
        gload16(gA[3] + ko, lA + 12288);                \
        gload16(gB[0] + ko, lB);                        \
        gload16(gB[1] + ko, lB + 4096);                 \
        gload16(gB[2] + ko, lB + 8192);                 \
        gload16(gB[3] + ko, lB + 12288); } while (0)

    const int sl = ((wid * 4 + quad) ^ m16) * 8;   // swizzled slot (16 slots)

    ISSUE(0);
    for (int kt = 0; kt < 8; ++kt) {     // K = 1024, BK = 128
        __syncthreads();
        f16x8 af[4], bf[4];
        #pragma unroll
        for (int i = 0; i < 4; ++i) {
            af[i] = *(const f16x8*)&Ash[(i * 16 + m16) * 128 + sl];
            bf[i] = *(const f16x8*)&Bsh[(i * 16 + m16) * 128 + sl];
        }
        __syncthreads();
        if (kt + 1 < 8) ISSUE(kt + 1);
        #pragma unroll
        for (int i = 0; i < 4; ++i)
            #pragma unroll
            for (int j = 0; j < 4; ++j)
                acc[i][j] = __builtin_amdgcn_mfma_f32_16x16x32_f16(
                                af[i], bf[j], acc[i][j], 0, 0, 0);
    }
    #undef ISSUE

    // tree reduce: waves 2,3 write -> waves 0,1 add; wave 1 write -> wave 0 add.
    #define XIDX(row, col) ((row) * 64 + ((col) ^ (((row) & 4) << 2)))
    #define WR(base) do {                                                       \
        _Pragma("unroll")                                                       \
        for (int i = 0; i < 4; ++i)                                             \
            _Pragma("unroll")                                                   \
            for (int j = 0; j < 4; ++j)                                         \
                _Pragma("unroll")                                               \
                for (int ri = 0; ri < 4; ++ri)                                  \
                    (base)[XIDX(i * 16 + quad * 4 + ri, j * 16 + m16)] = acc[i][j][ri]; \
        } while (0)
    #define RD(base) do {                                                       \
        _Pragma("unroll")                                                       \
        for (int i = 0; i < 4; ++i)                                             \
            _Pragma("unroll")                                                   \
            for (int j = 0; j < 4; ++j)                                         \
                _Pragma("unroll")                                               \
                for (int ri = 0; ri < 4; ++ri)                                  \
                    acc[i][j][ri] += (base)[XIDX(i * 16 + quad * 4 + ri, j * 16 + m16)]; \
        } while (0)

    __syncthreads();
    if (wid == 2) WR(xred);
    if (wid == 3) WR(xred + 4096);
    __syncthreads();
    if (wid == 0) RD(xred);
    if (wid == 1) RD(xred + 4096);
    __syncthreads();
    if (wid == 1) WR(xred);
    __syncthreads();
    if (wid == 0) {
        RD(xred);
        #pragma unroll
        for (int i = 0; i < 4; ++i)
            #pragma unroll
            for (int ri = 0; ri < 4; ++ri) {
                const size_t row = (size_t)(bm0 + i * 16 + quad * 4 + ri);
                f16* cp = C + row * LD + (bn0 + m16);
                #pragma unroll
                for (int j = 0; j < 4; ++j)
                    cp[j * 16] = (f16)acc[i][j][ri];
            }
    }
    #undef WR
    #undef RD
    #undef XIDX
}

// fp32 [R][C] -> fp16 [C][R]
__global__ __launch_bounds__(256)
void transpose_cast(const float* __restrict__ in, f16* __restrict__ out,
                    int R, int C)
{
    __shared__ float tile[64][65];
    const int c0 = blockIdx.x * 64, r0 = blockIdx.y * 64;
    const int tc = threadIdx.x & 63, tr = threadIdx.x >> 6;
    #pragma unroll
    for (int i = 0; i < 16; ++i)
        tile[tr + i * 4][tc] = in[(size_t)(r0 + tr + i * 4) * C + c0 + tc];
    __syncthreads();
    #pragma unroll
    for (int i = 0; i < 16; ++i)
        out[(size_t)(c0 + tr + i * 4) * R + r0 + tc] = (f16)tile[tc][tr + i * 4];
}

__global__ __launch_bounds__(256)
void cast_f16(const float* __restrict__ in, f16* __restrict__ out)
{
    const size_t i = ((size_t)blockIdx.x * 256 + threadIdx.x) * 4;
    float4 v = *(const float4*)(in + i);
    f16x4 o; o.x = (f16)v.x; o.y = (f16)v.y; o.z = (f16)v.z; o.w = (f16)v.w;
    *(f16x4*)(out + i) = o;
}

// three 1M-element fp32->f16 casts (wq, wk, wv)
__global__ __launch_bounds__(256)
void cast3_f16(const float* __restrict__ s0, const float* __restrict__ s1,
               const float* __restrict__ s2,
               f16* __restrict__ d0, f16* __restrict__ d1, f16* __restrict__ d2)
{
    const int z = blockIdx.z;
    const float* in = (z == 0) ? s0 : (z == 1) ? s1 : s2;
    f16* out = (z == 0) ? d0 : (z == 1) ? d1 : d2;
    const size_t i = ((size_t)blockIdx.x * 256 + threadIdx.x) * 4;
    float4 v = *(const float4*)(in + i);
    f16x4 o; o.x = (f16)v.x; o.y = (f16)v.y; o.z = (f16)v.z; o.w = (f16)v.w;
    *(f16x4*)(out + i) = o;
}

// in-place row softmax: reads fp32 row (2048), writes f16 probs into the
// first half of the same row (ldp = 4096 f16 = row pitch).
__global__ __launch_bounds__(256)
void softmax_f16(float* __restrict__ S)
{
    __shared__ float red[256];
    float* p = S + (size_t)blockIdx.x * 2048;
    f16* q = (f16*)p;
    const int t = threadIdx.x;

    float4 u0 = *(const float4*)(p + t * 4);
    float4 u1 = *(const float4*)(p + 1024 + t * 4);

    float m = fmaxf(fmaxf(fmaxf(u0.x, u0.y), fmaxf(u0.z, u0.w)),
                    fmaxf(fmaxf(u1.x, u1.y), fmaxf(u1.z, u1.w)));
    red[t] = m;
    __syncthreads();
    #pragma unroll
    for (int s = 128; s > 0; s >>= 1) {
        if (t < s) red[t] = fmaxf(red[t], red[t + s]);
        __syncthreads();
    }
    const float rowmax = red[0];
    __syncthreads();

    u0.x = __expf(u0.x - rowmax); u0.y = __expf(u0.y - rowmax);
    u0.z = __expf(u0.z - rowmax); u0.w = __expf(u0.w - rowmax);
    u1.x = __expf(u1.x - rowmax); u1.y = __expf(u1.y - rowmax);
    u1.z = __expf(u1.z - rowmax); u1.w = __expf(u1.w - rowmax);

    red[t] = (u0.x + u0.y + u0.z + u0.w) + (u1.x + u1.y + u1.z + u1.w);
    __syncthreads();
    #pragma unroll
    for (int s = 128; s > 0; s >>= 1) {
        if (t < s) red[t] += red[t + s];
        __syncthreads();
    }
    const float inv = 1.0f / red[0];
    __syncthreads();   // all reads of this row done before overwrite

    f16x4 o0, o1;
    o0.x = (f16)(u0.x * inv); o0.y = (f16)(u0.y * inv);
    o0.z = (f16)(u0.z * inv); o0.w = (f16)(u0.w * inv);
    o1.x = (f16)(u1.x * inv); o1.y = (f16)(u1.y * inv);
    o1.z = (f16)(u1.z * inv); o1.w = (f16)(u1.w * inv);
    *(f16x4*)(q + t * 4)        = o0;
    *(f16x4*)(q + 1024 + t * 4) = o1;
}

extern "C" void kernel_launch(void* const* d_in, const int* in_sizes, int n_in,
                              void* d_out, int out_size, void* d_ws, size_t ws_size,
                              hipStream_t stream)
{
    const float* x  = (const float*)d_in[0];
    const float* wq = (const float*)d_in[1];
    const float* wk = (const float*)d_in[2];
    const float* wv = (const float*)d_in[3];
    const float* wo = (const float*)d_in[4];
    const float* w1 = (const float*)d_in[5];
    const float* w2 = (const float*)d_in[6];
    float* out = (float*)d_out;

    const int S = 2048, D = 1024, DFF = 4096, Bb = 4;
    const int NTOK = Bb * S;  // 8192
    const size_t M1 = 1024 * 1024;

    // workspace (f16 units); peak 140 MB
    f16* W    = (f16*)d_ws;
    f16* xh   = W;                      // [0, 8M)
    f16* wqh  = W + 8 * M1;             // 1M each
    f16* wkh  = W + 9 * M1;
    f16* wvh  = W + 10 * M1;
    f16* woT  = W + 11 * M1;
    f16* w1T  = W + 12 * M1;            // 4M
    f16* w2T  = W + 16 * M1;            // 4M
    f16* wqkT = W + 20 * M1;            // 1M  (= wk @ wq^T)
    f16* wvoT = W + 21 * M1;            // 1M  (= (wv @ wo)^T)
    f16* qp   = W + 22 * M1;            // 8M  (q' = x @ Wqk)
    f16* vwT  = W + 30 * M1;            // 8M  ([1024][8192] = (x @ Wvo)^T)
    float* sb = (float*)(W + 38 * M1);  // 16M fp32 scores (64 MB)
    f16* ph   = (f16*)sb;               // probs in-place, row pitch 4096 f16
    f16* pj   = xh;                     // P @ vw  overwrites xh (dead)
    f16* hd   = qp;                     // hidden overwrites qp+vwT+sb regions

    dim3 blk(256);

    // casts / transposes / weight products
    cast_f16<<<dim3(NTOK * D / 1024), blk, 0, stream>>>(x, xh);
    cast3_f16<<<dim3(D * D / 1024, 1, 3), blk, 0, stream>>>(
        wq, wk, wv, wqh, wkh, wvh);
    transpose_cast<<<dim3(D / 64, D / 64), blk, 0, stream>>>(wo, woT, D, D);
    transpose_cast<<<dim3(DFF / 64, D / 64), blk, 0, stream>>>(w1, w1T, D, DFF);
    transpose_cast<<<dim3(D / 64, DFF / 64), blk, 0, stream>>>(w2, w2T, DFF, D);
    // wqkT = wk @ wq^T ; wvoT = NT(woT, wvh) = (wv @ wo)^T
    gemm_dd<<<dim3(16, 16, 2), blk, 0, stream>>>(
        wkh, wqh, wqkT, woT, wvh, wvoT);

    // q' = xh @ wqkT'   [8192][1024]
    gemm_f16<0><<<dim3(NTOK / BM, D / BN, 1), blk, 0, stream>>>(
        xh, wqkT, nullptr, qp, D, D, D, D, 0, 0, 0);
    // vwT = wvoT @ xh'  [1024][8192]
    gemm_f16<0><<<dim3(D / BM, NTOK / BN, 1), blk, 0, stream>>>(
        wvoT, xh, nullptr, vwT, D, D, D, NTOK, 0, 0, 0);

    // scores[b] = q'_b @ xh_b'   fp32 [2048][2048] x4
    gemm_f16<2><<<dim3(S / BM, S / BN, Bb), blk, 0, stream>>>(
        qp, xh, nullptr, sb, D, D, D, S,
        (long long)S * D, (long long)S * D, (long long)S * S);

    // softmax -> f16 probs in place (row pitch 4096)
    softmax_f16<<<dim3(NTOK), blk, 0, stream>>>(sb);

    // pj[b] = P_b @ (vwT[:, b-slice])'   [2048][1024] x4
    gemm_f16<0><<<dim3(S / BM, D / BN, Bb), blk, 0, stream>>>(
        ph, vwT, nullptr, pj, S, 4096, NTOK, D,
        (long long)S * 4096, (long long)S, (long long)S * D);

    // hidden = relu(pj @ w1T')   [8192][4096]  — R4-style kernel (941 TF)
    gemm_ns<1><<<dim3(NTOK / BM, DFF / BN, 1), blk, 0, stream>>>(
        pj, w1T, hd, D, D, D, DFF);

    // out = hd @ w2T' + x   fp32 [8192][1024]
    gemm_f16<3><<<dim3(NTOK / BM, D / BN, 1), blk, 0, stream>>>(
        hd, w2T, x, out, DFF, DFF, DFF, D, 0, 0, 0);
}